// Round 11
// baseline (494.152 us; speedup 1.0000x reference)
//
#include <hip/hip_runtime.h>
#include <math.h>

typedef unsigned int u32;

#define LRELU_SLOPE 0.2f

static __device__ __forceinline__ float lrelu(float x) {
  return x >= 0.f ? x : LRELU_SLOPE * x;
}
// bf16-pair helpers: a u32 holds two bf16 (low half = even element)
static __device__ __forceinline__ float bflo(u32 u) {
  return __builtin_bit_cast(float, u << 16);
}
static __device__ __forceinline__ float bfhi(u32 u) {
  return __builtin_bit_cast(float, u & 0xFFFF0000u);
}
static __device__ __forceinline__ u32 f2bf_pack(float a, float b) {  // RNE
  u32 ua = __builtin_bit_cast(u32, a), ub = __builtin_bit_cast(u32, b);
  ua = (ua + 0x7FFFu + ((ua >> 16) & 1u)) >> 16;
  ub = (ub + 0x7FFFu + ((ub >> 16) & 1u)) & 0xFFFF0000u;
  return ua | ub;
}

// ---------------- CSR construction (XCD-partitioned) ----------------
// Partition key space into 8 contiguous ranges; block (blockIdx&7) only handles
// entries whose DESTINATION key is in its partition. blockIdx&7 heuristically ==
// XCD (round-robin dispatch), so counter lines and CSR destination lines are
// touched by a single XCD's L2 -> full-line assembly, no cross-XCD ping-pong.
// Correctness does NOT depend on the mapping: every entry is processed exactly
// once per side because the partition function is deterministic.

__global__ __launch_bounds__(256) void countp_kernel(
    const int* __restrict__ node, const int* __restrict__ hedge, int nnz,
    int* __restrict__ cnt_n, int* __restrict__ cnt_e,
    float scale_n, float scale_e, int chunk) {
  int p = blockIdx.x & 7, q = blockIdx.x >> 3;
  int beg = q * chunk, end = min(nnz, beg + chunk);
  for (int i = beg + threadIdx.x; i < end; i += 256) {
    int he = hedge[i], nd = node[i];
    int pe = min(7, (int)((float)he * scale_e));
    int pn = min(7, (int)((float)nd * scale_n));
    if (pe == p) atomicAdd(&cnt_e[he], 1);
    if (pn == p) atomicAdd(&cnt_n[nd], 1);
  }
}

__global__ __launch_bounds__(256) void scatterp_kernel(
    const int* __restrict__ node, const int* __restrict__ hedge, int nnz,
    int* __restrict__ cur_n, int* __restrict__ cur_e,
    int* __restrict__ n_hedge, int* __restrict__ e_node,
    float scale_n, float scale_e, int chunk) {
  int p = blockIdx.x & 7, q = blockIdx.x >> 3;
  int beg = q * chunk, end = min(nnz, beg + chunk);
  for (int i = beg + threadIdx.x; i < end; i += 256) {
    int he = hedge[i], nd = node[i];
    if (min(7, (int)((float)he * scale_e)) == p)
      e_node[atomicAdd(&cur_e[he], 1)] = nd;
    if (min(7, (int)((float)nd * scale_n)) == p)
      n_hedge[atomicAdd(&cur_n[nd], 1)] = he;
  }
}

// per-1024-block exclusive scan + block sum; also emits 1/cnt
__global__ __launch_bounds__(256) void scan1_kernel(const int* __restrict__ cnt,
                                                    int* __restrict__ off,
                                                    int* __restrict__ bsum,
                                                    float* __restrict__ rec, int n) {
  int b = blockIdx.x, tid = threadIdx.x, lane = tid & 63, wid = tid >> 6;
  int i0 = b * 1024 + tid * 4;
  int v0 = (i0 + 0 < n) ? cnt[i0 + 0] : 0;
  int v1 = (i0 + 1 < n) ? cnt[i0 + 1] : 0;
  int v2 = (i0 + 2 < n) ? cnt[i0 + 2] : 0;
  int v3 = (i0 + 3 < n) ? cnt[i0 + 3] : 0;
  if (i0 + 0 < n) rec[i0 + 0] = v0 > 0 ? 1.f / (float)v0 : 0.f;
  if (i0 + 1 < n) rec[i0 + 1] = v1 > 0 ? 1.f / (float)v1 : 0.f;
  if (i0 + 2 < n) rec[i0 + 2] = v2 > 0 ? 1.f / (float)v2 : 0.f;
  if (i0 + 3 < n) rec[i0 + 3] = v3 > 0 ? 1.f / (float)v3 : 0.f;
  int s = v0 + v1 + v2 + v3;
  int incl = s;
  #pragma unroll
  for (int d = 1; d < 64; d <<= 1) {
    int t = __shfl_up(incl, d);
    if (lane >= d) incl += t;
  }
  __shared__ int ws[4];
  if (lane == 63) ws[wid] = incl;
  __syncthreads();
  int woff = 0;
  #pragma unroll
  for (int w = 0; w < 4; ++w)
    if (w < wid) woff += ws[w];
  int run = woff + incl - s;
  if (i0 + 0 < n) off[i0 + 0] = run; run += v0;
  if (i0 + 1 < n) off[i0 + 1] = run; run += v1;
  if (i0 + 2 < n) off[i0 + 2] = run; run += v2;
  if (i0 + 3 < n) off[i0 + 3] = run;
  if (tid == 0) bsum[b] = ws[0] + ws[1] + ws[2] + ws[3];
}

// scans both bsum arrays in one dispatch (grid=2, block=64)
__global__ void scan2_kernel(int* __restrict__ bsum_e, int nbe,
                             int* __restrict__ bsum_n, int nbn) {
  int* b = blockIdx.x == 0 ? bsum_e : bsum_n;
  int nb = blockIdx.x == 0 ? nbe : nbn;
  int tid = threadIdx.x;
  int v = (tid < nb) ? b[tid] : 0;
  int incl = v;
  #pragma unroll
  for (int d = 1; d < 64; d <<= 1) {
    int t = __shfl_up(incl, d);
    if (tid >= d) incl += t;
  }
  if (tid < nb) b[tid] = incl - v;
  if (tid == 63) b[64] = incl;
}

__global__ void scan3_kernel(int* __restrict__ off, const int* __restrict__ bsum,
                             int n, int* __restrict__ cur) {
  int i = blockIdx.x * blockDim.x + threadIdx.x;
  if (i < n) {
    int v = off[i] + bsum[i >> 10];
    off[i] = v;
    cur[i] = v;
  }
  if (i == n) off[n] = bsum[64];
}

// ---------------- GEMM1: [R,128]@[128,256] -> bf16, fused attention dot ----------------
// thread: c = tid&127 -> col pair {2c,2c+1}; rh = tid>>7 -> 16 rows. head = c>>5.

__global__ __launch_bounds__(256) void gemm1_kernel(
    const float* __restrict__ X, const float* __restrict__ W,
    u32* __restrict__ Yb, int R,
    const float* __restrict__ att, int half, float* __restrict__ adot) {
  __shared__ float xt[32][128];
  int r0 = blockIdx.x * 32, tid = threadIdx.x, lane = tid & 63;
  int c = tid & 127, rh = tid >> 7;
  for (int i = tid; i < 32 * 32; i += 256) {
    int r = i >> 5, k4 = i & 31;
    int rr = r0 + r;
    float4 v = rr < R ? reinterpret_cast<const float4*>(X)[(size_t)rr * 32 + k4]
                      : make_float4(0.f, 0.f, 0.f, 0.f);
    reinterpret_cast<float4*>(&xt[r][0])[k4] = v;
  }
  __syncthreads();
  float accA[16], accB[16];
  #pragma unroll
  for (int r = 0; r < 16; ++r) { accA[r] = 0.f; accB[r] = 0.f; }
  for (int k = 0; k < 128; k += 4) {
    float4 xv[16];
    #pragma unroll
    for (int r = 0; r < 16; ++r)
      xv[r] = *reinterpret_cast<const float4*>(&xt[rh * 16 + r][k]);
    #pragma unroll
    for (int kk = 0; kk < 4; ++kk) {
      float wa = W[(k + kk) * 256 + 2 * c];
      float wb = W[(k + kk) * 256 + 2 * c + 1];
      #pragma unroll
      for (int r = 0; r < 16; ++r) {
        float xr = (kk == 0) ? xv[r].x : (kk == 1) ? xv[r].y : (kk == 2) ? xv[r].z : xv[r].w;
        accA[r] = fmaf(xr, wa, accA[r]);
        accB[r] = fmaf(xr, wb, accB[r]);
      }
    }
  }
  if (Yb != nullptr) {
    #pragma unroll
    for (int r = 0; r < 16; ++r) {
      int rr = r0 + rh * 16 + r;
      if (rr < R) Yb[(size_t)rr * 128 + c] = f2bf_pack(accA[r], accB[r]);
    }
  }
  int hh = c >> 5, cl = c & 31;
  float avA = att[hh * 128 + half + 2 * cl];
  float avB = att[hh * 128 + half + 2 * cl + 1];
  #pragma unroll
  for (int r = 0; r < 16; ++r) {
    float p = fmaf(accA[r], avA, accB[r] * avB);
    #pragma unroll
    for (int s = 16; s >= 1; s >>= 1) p += __shfl_xor(p, s);
    int rr = r0 + rh * 16 + r;
    if ((lane & 31) == 0 && rr < R) adot[rr * 4 + hh] = p;
  }
}

// ---------------- GEMM2: [R,256]bf16 @ [256,64] -> bf16 ----------------
// thread: cp = tid&31 -> col pair {2cp,2cp+1}; rg = tid>>5 -> 4 rows.

__global__ __launch_bounds__(256) void gemm2_kernel(
    const u32* __restrict__ Hb, const float* __restrict__ W,
    u32* __restrict__ Yb, int R) {
  __shared__ u32 ht[32][128];
  int r0 = blockIdx.x * 32, tid = threadIdx.x;
  int cp = tid & 31, rg = tid >> 5;
  for (int i = tid; i < 32 * 32; i += 256) {
    int r = i >> 5, q = i & 31;
    int rr = r0 + r;
    uint4 v = rr < R ? reinterpret_cast<const uint4*>(Hb)[(size_t)rr * 32 + q]
                     : make_uint4(0u, 0u, 0u, 0u);
    reinterpret_cast<uint4*>(&ht[r][0])[q] = v;
  }
  __syncthreads();
  float acc[4][2] = {};
  for (int k = 0; k < 256; k += 4) {
    float w0a = W[(k + 0) * 64 + 2 * cp], w0b = W[(k + 0) * 64 + 2 * cp + 1];
    float w1a = W[(k + 1) * 64 + 2 * cp], w1b = W[(k + 1) * 64 + 2 * cp + 1];
    float w2a = W[(k + 2) * 64 + 2 * cp], w2b = W[(k + 2) * 64 + 2 * cp + 1];
    float w3a = W[(k + 3) * 64 + 2 * cp], w3b = W[(k + 3) * 64 + 2 * cp + 1];
    #pragma unroll
    for (int r = 0; r < 4; ++r) {
      uint2 u = *reinterpret_cast<const uint2*>(&ht[rg * 4 + r][k >> 1]);
      float x0 = bflo(u.x), x1 = bfhi(u.x), x2 = bflo(u.y), x3 = bfhi(u.y);
      acc[r][0] = fmaf(x0, w0a, acc[r][0]); acc[r][1] = fmaf(x0, w0b, acc[r][1]);
      acc[r][0] = fmaf(x1, w1a, acc[r][0]); acc[r][1] = fmaf(x1, w1b, acc[r][1]);
      acc[r][0] = fmaf(x2, w2a, acc[r][0]); acc[r][1] = fmaf(x2, w2b, acc[r][1]);
      acc[r][0] = fmaf(x3, w3a, acc[r][0]); acc[r][1] = fmaf(x3, w3b, acc[r][1]);
    }
  }
  #pragma unroll
  for (int r = 0; r < 4; ++r) {
    int rr = r0 + rg * 4 + r;
    if (rr < R) Yb[(size_t)rr * 32 + cp] = f2bf_pack(acc[r][0], acc[r][1]);
  }
}

// ---------------- p1: fused softmax (no max pass) + nodes->hyperedges gather ----
// Logits are bounded (|l| ~ 5), so exp without max-subtraction is safe and
// identical to the reference within fp32 rounding. One walk total.
// Stores ehp = Brec*rds * sum(exp*xh) as bf16, and pk[e][h] = (a_e, rds) for p2.

__global__ __launch_bounds__(256) void p1_kernel(
    const int* __restrict__ off_e, const int* __restrict__ e_node,
    const u32* __restrict__ xhb, const float* __restrict__ a_n,
    const float* __restrict__ a_e, const float* __restrict__ Brec,
    float2* __restrict__ pk, u32* __restrict__ ehb, int E) {
  int tid = threadIdx.x, lane = tid & 63;
  int wid = __builtin_amdgcn_readfirstlane(tid >> 6);
  int e = blockIdx.x * 4 + wid;
  if (e >= E) return;
  int beg = off_e[e], end = off_e[e + 1];
  int h = lane >> 4;
  float aeh = a_e[e * 4 + h];
  const uint2* rows = reinterpret_cast<const uint2*>(xhb);
  float4 A = make_float4(0.f, 0.f, 0.f, 0.f), B = A;
  float ls = 0.f;
  int m = beg;
  for (; m + 8 <= end; m += 8) {
    int ns[8]; float wsv[8];
    #pragma unroll
    for (int i = 0; i < 8; ++i) {
      ns[i] = e_node[m + i];
      wsv[i] = expf(lrelu(a_n[ns[i] * 4 + h] + aeh));
      ls += wsv[i];
    }
    uint2 vs[8];
    #pragma unroll
    for (int i = 0; i < 8; ++i) vs[i] = rows[(size_t)ns[i] * 64 + lane];
    #pragma unroll
    for (int i = 0; i < 8; ++i) {
      float4& C = (i & 1) ? B : A;
      C.x = fmaf(wsv[i], bflo(vs[i].x), C.x);
      C.y = fmaf(wsv[i], bfhi(vs[i].x), C.y);
      C.z = fmaf(wsv[i], bflo(vs[i].y), C.z);
      C.w = fmaf(wsv[i], bfhi(vs[i].y), C.w);
    }
  }
  if (m < end) {
    int last = end - 1;
    int ns[8]; float wsv[8];
    #pragma unroll
    for (int i = 0; i < 8; ++i) {
      int mm = m + i, mc = mm < last ? mm : last;
      ns[i] = e_node[mc];
      float w = expf(lrelu(a_n[ns[i] * 4 + h] + aeh));
      wsv[i] = (mm < end) ? w : 0.f;
      ls += wsv[i];
    }
    uint2 vs[8];
    #pragma unroll
    for (int i = 0; i < 8; ++i) vs[i] = rows[(size_t)ns[i] * 64 + lane];
    #pragma unroll
    for (int i = 0; i < 8; ++i) {
      float4& C = (i & 1) ? B : A;
      C.x = fmaf(wsv[i], bflo(vs[i].x), C.x);
      C.y = fmaf(wsv[i], bfhi(vs[i].x), C.y);
      C.z = fmaf(wsv[i], bflo(vs[i].y), C.z);
      C.w = fmaf(wsv[i], bfhi(vs[i].y), C.w);
    }
  }
  float rds = 1.f / (ls + 1e-16f);
  float sc = Brec[e] * rds;
  uint2 st;
  st.x = f2bf_pack((A.x + B.x) * sc, (A.y + B.y) * sc);
  st.y = f2bf_pack((A.z + B.z) * sc, (A.w + B.w) * sc);
  reinterpret_cast<uint2*>(ehb)[(size_t)e * 64 + lane] = st;
  if ((lane & 15) == 0) pk[e * 4 + h] = make_float2(aeh, rds);
}

// ---------------- p2: hyperedges->nodes gather, alpha recomputed from pk -------

__global__ __launch_bounds__(256) void p2_kernel(
    const int* __restrict__ off_n, const int* __restrict__ n_hedge,
    const u32* __restrict__ ehb, const float* __restrict__ a_n,
    const float2* __restrict__ pk, const float* __restrict__ Drec,
    const float* __restrict__ b1, u32* __restrict__ hactb, int N) {
  int tid = threadIdx.x, lane = tid & 63;
  int wid = __builtin_amdgcn_readfirstlane(tid >> 6);
  int n = blockIdx.x * 4 + wid;
  if (n >= N) return;
  int beg = off_n[n], end = off_n[n + 1];
  int h = lane >> 4;
  float anh = a_n[n * 4 + h];
  const uint2* rows = reinterpret_cast<const uint2*>(ehb);
  float4 A = make_float4(0.f, 0.f, 0.f, 0.f), B = A;
  int m = beg;
  for (; m + 8 <= end; m += 8) {
    int es[8]; float wsv[8];
    #pragma unroll
    for (int i = 0; i < 8; ++i) {
      es[i] = n_hedge[m + i];
      float2 pv = pk[es[i] * 4 + h];
      wsv[i] = expf(lrelu(anh + pv.x)) * pv.y;
    }
    uint2 vs[8];
    #pragma unroll
    for (int i = 0; i < 8; ++i) vs[i] = rows[(size_t)es[i] * 64 + lane];
    #pragma unroll
    for (int i = 0; i < 8; ++i) {
      float4& C = (i & 1) ? B : A;
      C.x = fmaf(wsv[i], bflo(vs[i].x), C.x);
      C.y = fmaf(wsv[i], bfhi(vs[i].x), C.y);
      C.z = fmaf(wsv[i], bflo(vs[i].y), C.z);
      C.w = fmaf(wsv[i], bfhi(vs[i].y), C.w);
    }
  }
  if (m < end) {
    int last = end - 1;
    int es[8]; float wsv[8];
    #pragma unroll
    for (int i = 0; i < 8; ++i) {
      int mm = m + i, mc = mm < last ? mm : last;
      es[i] = n_hedge[mc];
      float2 pv = pk[es[i] * 4 + h];
      float w = expf(lrelu(anh + pv.x)) * pv.y;
      wsv[i] = (mm < end) ? w : 0.f;
    }
    uint2 vs[8];
    #pragma unroll
    for (int i = 0; i < 8; ++i) vs[i] = rows[(size_t)es[i] * 64 + lane];
    #pragma unroll
    for (int i = 0; i < 8; ++i) {
      float4& C = (i & 1) ? B : A;
      C.x = fmaf(wsv[i], bflo(vs[i].x), C.x);
      C.y = fmaf(wsv[i], bfhi(vs[i].x), C.y);
      C.z = fmaf(wsv[i], bflo(vs[i].y), C.z);
      C.w = fmaf(wsv[i], bfhi(vs[i].y), C.w);
    }
  }
  float dr = Drec[n];
  float4 bb = reinterpret_cast<const float4*>(b1)[lane];
  float vx = fmaf(A.x + B.x, dr, bb.x);
  float vy = fmaf(A.y + B.y, dr, bb.y);
  float vz = fmaf(A.z + B.z, dr, bb.z);
  float vw = fmaf(A.w + B.w, dr, bb.w);
  vx = vx > 0.f ? vx : expm1f(vx);
  vy = vy > 0.f ? vy : expm1f(vy);
  vz = vz > 0.f ? vz : expm1f(vz);
  vw = vw > 0.f ? vw : expm1f(vw);
  uint2 st;
  st.x = f2bf_pack(vx, vy);
  st.y = f2bf_pack(vz, vw);
  reinterpret_cast<uint2*>(hactb)[(size_t)n * 64 + lane] = st;
}

// ---------------- layer-2 propagates (64 features) ----------------
// quarter-wave per member: f8 = lane&15 (uint2 of 4 bf16), mo = lane>>4.

__global__ __launch_bounds__(256) void p1b_kernel(
    const int* __restrict__ off_e, const int* __restrict__ e_node,
    const u32* __restrict__ xh2b, const float* __restrict__ Brec,
    float* __restrict__ eh2, int E) {
  int tid = threadIdx.x, lane = tid & 63;
  int wid = __builtin_amdgcn_readfirstlane(tid >> 6);
  int e = blockIdx.x * 4 + wid;
  if (e >= E) return;
  int f8 = lane & 15, mo = lane >> 4;
  int beg = off_e[e], end = off_e[e + 1];
  const uint2* rows = reinterpret_cast<const uint2*>(xh2b);
  float4 A = make_float4(0.f, 0.f, 0.f, 0.f), B = A;
  int m = beg;
  for (; m + 8 <= end; m += 8) {
    int n0 = e_node[m + mo], n1 = e_node[m + 4 + mo];
    uint2 u0 = rows[(size_t)n0 * 16 + f8];
    uint2 u1 = rows[(size_t)n1 * 16 + f8];
    A.x += bflo(u0.x); A.y += bfhi(u0.x); A.z += bflo(u0.y); A.w += bfhi(u0.y);
    B.x += bflo(u1.x); B.y += bfhi(u1.x); B.z += bflo(u1.y); B.w += bfhi(u1.y);
  }
  if (m < end) {
    int last = end - 1;
    int mm0 = m + mo, mm1 = m + 4 + mo;
    int mc0 = mm0 < last ? mm0 : last, mc1 = mm1 < last ? mm1 : last;
    int n0 = e_node[mc0], n1 = e_node[mc1];
    uint2 u0 = rows[(size_t)n0 * 16 + f8];
    uint2 u1 = rows[(size_t)n1 * 16 + f8];
    if (mm0 < end) { A.x += bflo(u0.x); A.y += bfhi(u0.x); A.z += bflo(u0.y); A.w += bfhi(u0.y); }
    if (mm1 < end) { B.x += bflo(u1.x); B.y += bfhi(u1.x); B.z += bflo(u1.y); B.w += bfhi(u1.y); }
  }
  A.x += B.x; A.y += B.y; A.z += B.z; A.w += B.w;
  A.x += __shfl_xor(A.x, 16); A.x += __shfl_xor(A.x, 32);
  A.y += __shfl_xor(A.y, 16); A.y += __shfl_xor(A.y, 32);
  A.z += __shfl_xor(A.z, 16); A.z += __shfl_xor(A.z, 32);
  A.w += __shfl_xor(A.w, 16); A.w += __shfl_xor(A.w, 32);
  if (mo == 0) {
    float sc = Brec[e];
    float4 o = make_float4(A.x * sc, A.y * sc, A.z * sc, A.w * sc);
    reinterpret_cast<float4*>(eh2)[(size_t)e * 16 + f8] = o;
  }
}

__global__ __launch_bounds__(256) void p2b_kernel(
    const int* __restrict__ off_n, const int* __restrict__ n_hedge,
    const float* __restrict__ eh2, const float* __restrict__ Drec,
    const float* __restrict__ b2, float* __restrict__ out, int N) {
  int tid = threadIdx.x, lane = tid & 63;
  int wid = __builtin_amdgcn_readfirstlane(tid >> 6);
  int n = blockIdx.x * 4 + wid;
  if (n >= N) return;
  int f8 = lane & 15, mo = lane >> 4;
  int beg = off_n[n], end = off_n[n + 1];
  const float4* rows = reinterpret_cast<const float4*>(eh2);
  float4 A = make_float4(0.f, 0.f, 0.f, 0.f), B = A;
  int m = beg;
  for (; m + 8 <= end; m += 8) {
    int e0 = n_hedge[m + mo], e1 = n_hedge[m + 4 + mo];
    float4 v0 = rows[(size_t)e0 * 16 + f8];
    float4 v1 = rows[(size_t)e1 * 16 + f8];
    A.x += v0.x; A.y += v0.y; A.z += v0.z; A.w += v0.w;
    B.x += v1.x; B.y += v1.y; B.z += v1.z; B.w += v1.w;
  }
  if (m < end) {
    int last = end - 1;
    int mm0 = m + mo, mm1 = m + 4 + mo;
    int mc0 = mm0 < last ? mm0 : last, mc1 = mm1 < last ? mm1 : last;
    int e0 = n_hedge[mc0], e1 = n_hedge[mc1];
    float4 v0 = rows[(size_t)e0 * 16 + f8];
    float4 v1 = rows[(size_t)e1 * 16 + f8];
    if (mm0 < end) { A.x += v0.x; A.y += v0.y; A.z += v0.z; A.w += v0.w; }
    if (mm1 < end) { B.x += v1.x; B.y += v1.y; B.z += v1.z; B.w += v1.w; }
  }
  A.x += B.x; A.y += B.y; A.z += B.z; A.w += B.w;
  A.x += __shfl_xor(A.x, 16); A.x += __shfl_xor(A.x, 32);
  A.y += __shfl_xor(A.y, 16); A.y += __shfl_xor(A.y, 32);
  A.z += __shfl_xor(A.z, 16); A.z += __shfl_xor(A.z, 32);
  A.w += __shfl_xor(A.w, 16); A.w += __shfl_xor(A.w, 32);
  if (mo == 0) {
    float dr = Drec[n];
    float4 bb = reinterpret_cast<const float4*>(b2)[f8];
    float4 o = make_float4(fmaf(A.x, dr, bb.x), fmaf(A.y, dr, bb.y),
                           fmaf(A.z, dr, bb.z), fmaf(A.w, dr, bb.w));
    reinterpret_cast<float4*>(out)[(size_t)n * 16 + f8] = o;
  }
}

// ---------------- launch ----------------

extern "C" void kernel_launch(void* const* d_in, const int* in_sizes, int n_in,
                              void* d_out, int out_size, void* d_ws, size_t ws_size,
                              hipStream_t stream) {
  const float* x   = (const float*)d_in[0];
  const int*   ei  = (const int*)d_in[1];
  const float* hea = (const float*)d_in[2];
  const float* W1  = (const float*)d_in[3];
  const float* att = (const float*)d_in[4];
  const float* b1  = (const float*)d_in[5];
  const float* W2  = (const float*)d_in[6];
  const float* b2  = (const float*)d_in[7];

  const int C2  = in_sizes[7];            // 64
  const int CH  = in_sizes[6] / C2;       // 256
  const int CIN = in_sizes[3] / CH;       // 128
  const int N   = in_sizes[0] / CIN;      // 50000
  const int E   = in_sizes[2] / CIN;      // 10000
  const int NNZ = in_sizes[1] / 2;        // 600000
  const int* node  = ei;
  const int* hedge = ei + NNZ;

  char* wp = (char*)d_ws;
  auto alloc = [&](size_t bytes) -> void* {
    void* p = (void*)wp;
    wp += (bytes + 255) & ~(size_t)255;
    return p;
  };
  u32*    xhb     = (u32*)   alloc((size_t)N * (CH / 2) * 4);  // bf16 [N][256]
  u32*    ehb     = (u32*)   alloc((size_t)E * (CH / 2) * 4);  // bf16 [E][256]
  u32*    hactb   = (u32*)   alloc((size_t)N * (CH / 2) * 4);  // bf16 [N][256]
  u32*    xh2b    = (u32*)   alloc((size_t)N * (C2 / 2) * 4);  // bf16 [N][64]
  float*  eh2     = (float*) alloc((size_t)E * C2 * 4);        // fp32 [E][64]
  float*  a_n     = (float*) alloc((size_t)N * 4 * 4);
  float*  a_e     = (float*) alloc((size_t)E * 4 * 4);
  float2* pk      = (float2*)alloc((size_t)E * 4 * 8);
  float*  Brec    = (float*) alloc((size_t)E * 4);
  float*  Drec    = (float*) alloc((size_t)N * 4);
  int*    cnt_e   = (int*)   alloc((size_t)E * 4);
  int*    cnt_n   = (int*)   alloc((size_t)N * 4);
  int*    off_e   = (int*)   alloc((size_t)(E + 1) * 4);
  int*    off_n   = (int*)   alloc((size_t)(N + 1) * 4);
  int*    cur_e   = (int*)   alloc((size_t)E * 4);
  int*    cur_n   = (int*)   alloc((size_t)N * 4);
  int*    e_node  = (int*)   alloc((size_t)NNZ * 4);
  int*    n_hedge = (int*)   alloc((size_t)NNZ * 4);
  int*    bsum_e  = (int*)   alloc(65 * 4);
  int*    bsum_n  = (int*)   alloc(65 * 4);

  hipMemsetAsync(cnt_e, 0, (size_t)E * 4, stream);
  hipMemsetAsync(cnt_n, 0, (size_t)N * 4, stream);

  const float scale_e = 8.0f / (float)E;
  const float scale_n = 8.0f / (float)N;
  const int BPP = 256;
  const int chunk = (NNZ + BPP - 1) / BPP;

  countp_kernel<<<8 * BPP, 256, 0, stream>>>(node, hedge, NNZ, cnt_n, cnt_e,
                                             scale_n, scale_e, chunk);

  int nbE = (E + 1023) / 1024, nbN = (N + 1023) / 1024;
  scan1_kernel<<<nbE, 256, 0, stream>>>(cnt_e, off_e, bsum_e, Brec, E);
  scan1_kernel<<<nbN, 256, 0, stream>>>(cnt_n, off_n, bsum_n, Drec, N);
  scan2_kernel<<<2, 64, 0, stream>>>(bsum_e, nbE, bsum_n, nbN);
  scan3_kernel<<<(E + 1 + 255) / 256, 256, 0, stream>>>(off_e, bsum_e, E, cur_e);
  scan3_kernel<<<(N + 1 + 255) / 256, 256, 0, stream>>>(off_n, bsum_n, N, cur_n);

  scatterp_kernel<<<8 * BPP, 256, 0, stream>>>(node, hedge, NNZ, cur_n, cur_e,
                                               n_hedge, e_node, scale_n, scale_e, chunk);

  gemm1_kernel<<<(N + 31) / 32, 256, 0, stream>>>(x, W1, xhb, N, att, 0, a_n);
  gemm1_kernel<<<(E + 31) / 32, 256, 0, stream>>>(hea, W1, nullptr, E, att, 64, a_e);

  p1_kernel<<<(E + 3) / 4, 256, 0, stream>>>(off_e, e_node, xhb, a_n, a_e,
                                             Brec, pk, ehb, E);
  p2_kernel<<<(N + 3) / 4, 256, 0, stream>>>(off_n, n_hedge, ehb, a_n, pk,
                                             Drec, b1, hactb, N);

  gemm2_kernel<<<(N + 31) / 32, 256, 0, stream>>>(hactb, W2, xh2b, N);
  p1b_kernel<<<(E + 3) / 4, 256, 0, stream>>>(off_e, e_node, xh2b, Brec, eh2, E);
  p2b_kernel<<<(N + 3) / 4, 256, 0, stream>>>(off_n, n_hedge, eh2, Drec, b2,
                                              (float*)d_out, N);
}